// Round 6
// baseline (102.188 us; speedup 1.0000x reference)
//
#include <hip/hip_runtime.h>
#include <hip/hip_bf16.h>

#define NPTS 4096
#define NROWS 8192   // B*N
#define DIM 128
#define RPW 8        // rows per block (all 4 waves cooperate)
#define CAP 8        // per-(row,quarter) hit buffer: 4 global top + ties

typedef __attribute__((ext_vector_type(8))) short bf16x8;
typedef __attribute__((ext_vector_type(4))) float f32x4;

// ---------- prep: pos -> float4[8192], W -> W^T bf16 (verified) ----------
__global__ __launch_bounds__(256) void prep(const float* __restrict__ pos,
                                            const float* __restrict__ W,
                                            float4* __restrict__ pos4,
                                            __hip_bfloat16* __restrict__ Wt) {
    int t = blockIdx.x * 256 + threadIdx.x;
    if (t < NROWS) {
        const float* p = pos + (size_t)t * 3;
        pos4[t] = make_float4(p[0], p[1], p[2], 0.f);
    } else if (t < NROWS + DIM * DIM) {
        int i = t - NROWS;
        int n = i >> 7, k = i & 127;
        Wt[i] = __float2bfloat16(W[k * DIM + n]);  // Wt[n][k] = W[k][n]
    }
}

// ---------- xW = x @ W via bf16 MFMA, output bf16 (verified) ----------
__global__ __launch_bounds__(256) void xw_mfma(const float* __restrict__ x,
                                               const __hip_bfloat16* __restrict__ Wt,
                                               __hip_bfloat16* __restrict__ xWb) {
    int wave = threadIdx.x >> 6;
    int lane = threadIdx.x & 63;
    int tile = blockIdx.x * 4 + wave;          // 0..4095
    int m0 = (tile >> 3) << 4;
    int n0 = (tile & 7) << 4;
    int r = lane & 15;
    int kg = lane >> 4;                        // 0..3
    const float* xr = x + (size_t)(m0 + r) * DIM + kg * 8;
    const __hip_bfloat16* br = Wt + (size_t)(n0 + r) * DIM + kg * 8;
    f32x4 acc = {0.f, 0.f, 0.f, 0.f};
#pragma unroll
    for (int kb = 0; kb < 4; ++kb) {
        float4 a0 = *(const float4*)(xr + kb * 32);
        float4 a1 = *(const float4*)(xr + kb * 32 + 4);
        bf16x8 af;
        union { __hip_bfloat16 h; short s; } u;
        u.h = __float2bfloat16(a0.x); af[0] = u.s;
        u.h = __float2bfloat16(a0.y); af[1] = u.s;
        u.h = __float2bfloat16(a0.z); af[2] = u.s;
        u.h = __float2bfloat16(a0.w); af[3] = u.s;
        u.h = __float2bfloat16(a1.x); af[4] = u.s;
        u.h = __float2bfloat16(a1.y); af[5] = u.s;
        u.h = __float2bfloat16(a1.z); af[6] = u.s;
        u.h = __float2bfloat16(a1.w); af[7] = u.s;
        bf16x8 bfr = *(const bf16x8*)(br + kb * 32);
        acc = __builtin_amdgcn_mfma_f32_16x16x32_bf16(af, bfr, acc, 0, 0, 0);
    }
    int col = n0 + r;
    int rbase = m0 + (kg << 2);
#pragma unroll
    for (int reg = 0; reg < 4; ++reg)
        xWb[(size_t)(rbase + reg) * DIM + col] = __float2bfloat16(acc[reg]);
}

// Bit-identical d^2 in pass 1 and pass 2 (explicit fmaf => fixed rounding).
__device__ __forceinline__ float dist2(float4 q, float4 p) {
    float dx = q.x - p.x, dy = q.y - p.y, dz = q.z - p.z;
    return fmaf(dx, dx, fmaf(dy, dy, dz * dz));
}

// sorted-ascending insert: 7 v_min/max_f32
__device__ __forceinline__ void vins(float& k0, float& k1, float& k2, float& k3,
                                     float s) {
    float c = fmaxf(k0, s); k0 = fminf(k0, s);
    float t = fmaxf(k1, c); k1 = fminf(k1, c); c = t;
    t = fmaxf(k2, c);       k2 = fminf(k2, c); c = t;
    k3 = fminf(k3, c);
}

// merge two sorted-asc 4-lists -> 4 smallest sorted: 12 v_min/max_f32
__device__ __forceinline__ void vmerge(float& a0, float& a1, float& a2, float& a3,
                                       float b0, float b1, float b2, float b3) {
    float m0 = fminf(a0, b3), m1 = fminf(a1, b2);
    float m2 = fminf(a2, b1), m3 = fminf(a3, b0);
    float t0 = fminf(m0, m2), t2 = fmaxf(m0, m2);
    float t1 = fminf(m1, m3), t3 = fmaxf(m1, m3);
    a0 = fminf(t0, t1); a1 = fmaxf(t0, t1);
    a2 = fminf(t2, t3); a3 = fmaxf(t2, t3);
}

// Block = 8 rows, 4 waves; wave w scans quarter w (1024 candidates, 16 iters).
// Pass1: f32 value-only top4 per row -> exact global 4th value via LDS merge.
// Pass2: ballot threshold rescan -> per-(row,quarter) hit lists.
// Finalize: exact f64 (d2|j) rank over <=32 hits. Epilogue on all 4 waves.
__global__ __launch_bounds__(256, 4) void topk_agg(const float4* __restrict__ pos4,
                                                   const __hip_bfloat16* __restrict__ xWb,
                                                   const float* __restrict__ bias,
                                                   float* __restrict__ out) {
    int lane = threadIdx.x & 63;
    int wave = threadIdx.x >> 6;               // quarter 0..3
    int rowbase = blockIdx.x * RPW;            // 8 rows/block
    int batch = rowbase >> 12;
    int ibase = rowbase & (NPTS - 1);
    const float4* pb = pos4 + (size_t)batch * NPTS;

    __shared__ float4   vx4[4][RPW];           // [quarter][row] sorted-4 values
    __shared__ unsigned hidx[RPW][4][CAP];
    __shared__ float    hdva[RPW][4][CAP];
    __shared__ unsigned hcnt[RPW][4];
    __shared__ unsigned fidx[RPW][4];
    __shared__ float    fdst[RPW][4];

    float4 q[RPW];
#pragma unroll
    for (int r = 0; r < RPW; ++r) q[r] = pb[ibase + r];

    const float INF = __int_as_float(0x7f800000);
    float a0[RPW], a1[RPW], a2[RPW], a3[RPW];
#pragma unroll
    for (int r = 0; r < RPW; ++r) { a0[r] = a1[r] = a2[r] = a3[r] = INF; }

    int jbase = (wave << 10) + lane;

    // ---- pass 1: value-only scan, 16 iters ----
#pragma unroll 4
    for (int t = 0; t < 16; ++t) {
        float4 p = pb[jbase + (t << 6)];
#pragma unroll
        for (int r = 0; r < RPW; ++r)
            vins(a0[r], a1[r], a2[r], a3[r], dist2(q[r], p));
    }
    // intra-wave butterfly per row
#pragma unroll
    for (int off = 1; off < 64; off <<= 1) {
#pragma unroll
        for (int r = 0; r < RPW; ++r) {
            float p0 = __shfl_xor(a0[r], off), p1 = __shfl_xor(a1[r], off);
            float p2 = __shfl_xor(a2[r], off), p3 = __shfl_xor(a3[r], off);
            vmerge(a0[r], a1[r], a2[r], a3[r], p0, p1, p2, p3);
        }
    }
    // publish sorted-4 per (quarter,row); merge other quarters (all waves same)
    if (lane == 0) {
#pragma unroll
        for (int r = 0; r < RPW; ++r)
            vx4[wave][r] = make_float4(a0[r], a1[r], a2[r], a3[r]);
    }
    __syncthreads();
#pragma unroll
    for (int qq = 0; qq < 4; ++qq) {
        if (qq == wave) continue;
#pragma unroll
        for (int r = 0; r < RPW; ++r) {
            float4 o = vx4[qq][r];
            vmerge(a0[r], a1[r], a2[r], a3[r], o.x, o.y, o.z, o.w);
        }
    }
    // a3[r] = exact global 4th-smallest d2 for row r

    // ---- pass 2: threshold rescan -> hit lists (no atomics) ----
    unsigned cnt[RPW];
#pragma unroll
    for (int r = 0; r < RPW; ++r) cnt[r] = 0;
#pragma unroll 2
    for (int t = 0; t < 16; ++t) {
        int j = jbase + (t << 6);
        float4 p = pb[j];
#pragma unroll
        for (int r = 0; r < RPW; ++r) {
            float d = dist2(q[r], p);
            bool h = d <= a3[r];
            unsigned long long m = __ballot(h);
            if (m) {
                if (h) {
                    unsigned posn = cnt[r] +
                        (unsigned)__popcll(m & ((1ull << lane) - 1));
                    if (posn < CAP) { hidx[r][wave][posn] = (unsigned)j;
                                      hdva[r][wave][posn] = d; }
                }
                cnt[r] += (unsigned)__popcll(m);
            }
        }
    }
    if (lane == 0) {
#pragma unroll
        for (int r = 0; r < RPW; ++r)
            hcnt[r][wave] = cnt[r] < CAP ? cnt[r] : CAP;
    }
    __syncthreads();

    // ---- finalize: wave w ranks rows 2w (lanes 0-31) and 2w+1 (lanes 32-63) ----
    {
        int r = 2 * wave + (lane >> 5);
        int e = lane & 31;
        int qq = e >> 3, slot = e & 7;
        bool valid = (unsigned)slot < hcnt[r][qq];
        unsigned jj = 0; float dd = 0.f;
        if (valid) { jj = hidx[r][qq][slot]; dd = hdva[r][qq][slot]; }
        double key = valid
            ? __longlong_as_double(__double_as_longlong((double)dd) |
                                   (unsigned long long)jj)
            : __builtin_inf();
        int base = lane & 32;
        int rank = 0;
#pragma unroll
        for (int s = 0; s < 32; ++s) {
            double ks = __shfl(key, base + s);
            rank += (ks < key) ? 1 : 0;
        }
        if (valid && rank < 4) {
            fidx[r][rank] = jj;
            fdst[r][rank] = dd;
        }
    }
    __syncthreads();

    // ---- epilogue: wave w writes rows 2w, 2w+1; lane owns channels 2l,2l+1 ----
    int c = lane << 1;
    float2 bb = *(const float2*)(bias + c);
    const unsigned short* xu = (const unsigned short*)xWb;
    size_t bbase = ((size_t)batch * NPTS) << 7;
#pragma unroll
    for (int kk = 0; kk < 2; ++kk) {
        int r = 2 * wave + kk;
        unsigned i0 = fidx[r][0], i1 = fidx[r][1];
        unsigned i2 = fidx[r][2], i3 = fidx[r][3];
        float d0 = fdst[r][0], d1 = fdst[r][1];
        float d2 = fdst[r][2], d3 = fdst[r][3];
        float w0 = __expf(-(d0 + 1e-8f) * 0.5f);
        float w1 = __expf(-(d1 + 1e-8f) * 0.5f);
        float w2 = __expf(-(d2 + 1e-8f) * 0.5f);
        float w3 = __expf(-(d3 + 1e-8f) * 0.5f);
        float inv = 1.0f / (w0 + w1 + w2 + w3 + 1e-8f);
        w0 *= inv; w1 *= inv; w2 *= inv; w3 *= inv;
        ushort2 g0 = *(const ushort2*)(xu + bbase + ((size_t)i0 << 7) + c);
        ushort2 g1 = *(const ushort2*)(xu + bbase + ((size_t)i1 << 7) + c);
        ushort2 g2 = *(const ushort2*)(xu + bbase + ((size_t)i2 << 7) + c);
        ushort2 g3 = *(const ushort2*)(xu + bbase + ((size_t)i3 << 7) + c);
        float ox = bb.x + w0 * __uint_as_float((unsigned)g0.x << 16)
                        + w1 * __uint_as_float((unsigned)g1.x << 16)
                        + w2 * __uint_as_float((unsigned)g2.x << 16)
                        + w3 * __uint_as_float((unsigned)g3.x << 16);
        float oy = bb.y + w0 * __uint_as_float((unsigned)g0.y << 16)
                        + w1 * __uint_as_float((unsigned)g1.y << 16)
                        + w2 * __uint_as_float((unsigned)g2.y << 16)
                        + w3 * __uint_as_float((unsigned)g3.y << 16);
        *(float2*)(out + (((size_t)(rowbase + r)) << 7) + c) = make_float2(ox, oy);
    }
}

extern "C" void kernel_launch(void* const* d_in, const int* in_sizes, int n_in,
                              void* d_out, int out_size, void* d_ws, size_t ws_size,
                              hipStream_t stream) {
    const float* x    = (const float*)d_in[0];  // [2,4096,128]
    const float* pos  = (const float*)d_in[1];  // [2,4096,3]
    const float* W    = (const float*)d_in[2];  // [128,128]
    const float* bias = (const float*)d_in[3];  // [128]
    float* out = (float*)d_out;                 // [2,4096,128] f32

    char* ws = (char*)d_ws;
    __hip_bfloat16* xWb = (__hip_bfloat16*)ws;                       // 2 MB
    float4* pos4 = (float4*)(ws + (size_t)NROWS * DIM * 2);          // 128 KB
    __hip_bfloat16* Wt = (__hip_bfloat16*)(ws + (size_t)NROWS * DIM * 2
                                              + (size_t)NROWS * 16); // 32 KB

    prep<<<(NROWS + DIM * DIM + 255) / 256, 256, 0, stream>>>(pos, W, pos4, Wt);
    xw_mfma<<<(NROWS / 16) * (DIM / 16) / 4, 256, 0, stream>>>(x, Wt, xWb);
    topk_agg<<<NROWS / RPW, 256, 0, stream>>>(pos4, xWb, bias, out);
}

// Round 7
// 88.783 us; speedup vs baseline: 1.1510x; 1.1510x over previous
//
#include <hip/hip_runtime.h>
#include <hip/hip_bf16.h>

#define NPTS 4096
#define NROWS 8192   // B*N
#define DIM 128
#define GEMM_BLOCKS 1024   // 4096 16x16 tiles / 4 waves

typedef __attribute__((ext_vector_type(8))) short bf16x8;
typedef __attribute__((ext_vector_type(4))) float f32x4;

// ---------- K1: fused pos-repack + xW GEMM (self-contained W) ----------
// Blocks [0,1024): one wave per 16x16 tile of xW = x @ W via bf16 MFMA.
//   B-frag loaded straight from f32 W (row-major [k][n]) with scalar loads +
//   in-register bf16 cvt — no prep dependency, so safe to fuse.
// Blocks [1024,1056): repack pos (f32x3) -> pos4 (float4) for topk.
__global__ __launch_bounds__(256) void k1_prep_gemm(const float* __restrict__ x,
                                                    const float* __restrict__ pos,
                                                    const float* __restrict__ W,
                                                    float4* __restrict__ pos4,
                                                    __hip_bfloat16* __restrict__ xWb) {
    int b = blockIdx.x;
    if (b >= GEMM_BLOCKS) {
        int t = (b - GEMM_BLOCKS) * 256 + threadIdx.x;   // 0..8191
        const float* p = pos + (size_t)t * 3;
        pos4[t] = make_float4(p[0], p[1], p[2], 0.f);
        return;
    }
    int wave = threadIdx.x >> 6;
    int lane = threadIdx.x & 63;
    int tile = b * 4 + wave;                   // 0..4095
    int m0 = (tile >> 3) << 4;
    int n0 = (tile & 7) << 4;
    int r = lane & 15;
    int kg = lane >> 4;                        // 0..3
    const float* xr = x + (size_t)(m0 + r) * DIM + kg * 8;
    const float* wc = W + (size_t)(kg * 8) * DIM + (n0 + r);  // W[kg*8 + .][n0+r]
    f32x4 acc = {0.f, 0.f, 0.f, 0.f};
    union { __hip_bfloat16 h; short s; } u;
#pragma unroll
    for (int kb = 0; kb < 4; ++kb) {
        float4 a0 = *(const float4*)(xr + kb * 32);
        float4 a1 = *(const float4*)(xr + kb * 32 + 4);
        bf16x8 af, bf;
        u.h = __float2bfloat16(a0.x); af[0] = u.s;
        u.h = __float2bfloat16(a0.y); af[1] = u.s;
        u.h = __float2bfloat16(a0.z); af[2] = u.s;
        u.h = __float2bfloat16(a0.w); af[3] = u.s;
        u.h = __float2bfloat16(a1.x); af[4] = u.s;
        u.h = __float2bfloat16(a1.y); af[5] = u.s;
        u.h = __float2bfloat16(a1.z); af[6] = u.s;
        u.h = __float2bfloat16(a1.w); af[7] = u.s;
#pragma unroll
        for (int i = 0; i < 8; ++i) {
            u.h = __float2bfloat16(wc[(size_t)(kb * 32 + i) * DIM]);
            bf[i] = u.s;
        }
        acc = __builtin_amdgcn_mfma_f32_16x16x32_bf16(af, bf, acc, 0, 0, 0);
    }
    int col = n0 + r;
    int rbase = m0 + (kg << 2);
#pragma unroll
    for (int reg = 0; reg < 4; ++reg)
        xWb[(size_t)(rbase + reg) * DIM + col] = __float2bfloat16(acc[reg]);
}

// ---------- exact f64 packed key: key = f64(d2) with low 12 bits = j ----------
__device__ __forceinline__ double mkkey(float d2, int j) {
    return __longlong_as_double(__double_as_longlong((double)d2) |
                                (unsigned long long)(unsigned)j);
}

// sorted-ascending insert: 7 v_min/max_f64
__device__ __forceinline__ void kins(double& k0, double& k1, double& k2,
                                     double& k3, double s) {
    double c = fmax(k0, s); k0 = fmin(k0, s);
    double t = fmax(k1, c); k1 = fmin(k1, c); c = t;
    t = fmax(k2, c);        k2 = fmin(k2, c); c = t;
    k3 = fmin(k3, c);
}

// merge two sorted-asc 4-lists -> 4 smallest sorted: 12 v_min/max_f64
__device__ __forceinline__ void kmerge(double& a0, double& a1, double& a2,
                                       double& a3, double b0, double b1,
                                       double b2, double b3) {
    double m0 = fmin(a0, b3), m1 = fmin(a1, b2);
    double m2 = fmin(a2, b1), m3 = fmin(a3, b0);
    double t0 = fmin(m0, m2), t2 = fmax(m0, m2);
    double t1 = fmin(m1, m3), t3 = fmax(m1, m3);
    a0 = fmin(t0, t1); a1 = fmax(t0, t1);
    a2 = fmin(t2, t3); a3 = fmax(t2, t3);
}

// ---------- K2: R4-verbatim topk (best measured) + unroll 8 ----------
__global__ __launch_bounds__(256) void topk_agg(const float4* __restrict__ pos4,
                                                const __hip_bfloat16* __restrict__ xWb,
                                                const float* __restrict__ bias,
                                                float* __restrict__ out) {
    int lane = threadIdx.x & 63;
    int wave = threadIdx.x >> 6;
    int group = wave >> 1;
    int half = wave & 1;
    int rowbase = blockIdx.x * 4 + group * 2;   // 4 rows/block
    int batch = rowbase >> 12;
    int ibase = rowbase & (NPTS - 1);
    const float4* pb = pos4 + (size_t)batch * NPTS;

    float4 q0 = pb[ibase], q1 = pb[ibase + 1];
    const double INF = __builtin_inf();
    double a0 = INF, a1 = INF, a2 = INF, a3 = INF;   // row 0 keys
    double b0 = INF, b1 = INF, b2 = INF, b3 = INF;   // row 1 keys

    int jbase = (half << 11) + lane;
#pragma unroll 8
    for (int t = 0; t < 32; ++t) {
        int j = jbase + (t << 6);
        float4 p = pb[j];
        float dx = q0.x - p.x, dy = q0.y - p.y, dz = q0.z - p.z;
        float d2 = fmaf(dx, dx, fmaf(dy, dy, dz * dz));
        kins(a0, a1, a2, a3, mkkey(d2, j));
        dx = q1.x - p.x; dy = q1.y - p.y; dz = q1.z - p.z;
        d2 = fmaf(dx, dx, fmaf(dy, dy, dz * dz));
        kins(b0, b1, b2, b3, mkkey(d2, j));
    }

    // intra-wave butterfly: 6 xor steps, bitonic merge each
#pragma unroll
    for (int off = 1; off < 64; off <<= 1) {
        double p0 = __shfl_xor(a0, off), p1 = __shfl_xor(a1, off);
        double p2 = __shfl_xor(a2, off), p3 = __shfl_xor(a3, off);
        kmerge(a0, a1, a2, a3, p0, p1, p2, p3);
        p0 = __shfl_xor(b0, off); p1 = __shfl_xor(b1, off);
        p2 = __shfl_xor(b2, off); p3 = __shfl_xor(b3, off);
        kmerge(b0, b1, b2, b3, p0, p1, p2, p3);
    }

    // cross-half exchange via LDS
    __shared__ double lds[2][2][2][4];   // [group][half][row][slot]
    if (lane == 0) {
        lds[group][half][0][0] = a0; lds[group][half][0][1] = a1;
        lds[group][half][0][2] = a2; lds[group][half][0][3] = a3;
        lds[group][half][1][0] = b0; lds[group][half][1][1] = b1;
        lds[group][half][1][2] = b2; lds[group][half][1][3] = b3;
    }
    __syncthreads();
    if (half) return;

    kmerge(a0, a1, a2, a3, lds[group][1][0][0], lds[group][1][0][1],
                           lds[group][1][0][2], lds[group][1][0][3]);
    kmerge(b0, b1, b2, b3, lds[group][1][1][0], lds[group][1][1][1],
                           lds[group][1][1][2], lds[group][1][1][3]);

    // epilogue: lane owns channels (2*lane, 2*lane+1)
    int c = lane << 1;
    float2 bb = *(const float2*)(bias + c);
    const unsigned short* xu = (const unsigned short*)xWb;
    size_t bbase = ((size_t)batch * NPTS) << 7;
#pragma unroll
    for (int k = 0; k < 2; ++k) {
        double k0 = k ? b0 : a0, k1 = k ? b1 : a1;
        double k2 = k ? b2 : a2, k3 = k ? b3 : a3;
        unsigned i0 = (unsigned)__double_as_longlong(k0) & 0xFFFu;
        unsigned i1 = (unsigned)__double_as_longlong(k1) & 0xFFFu;
        unsigned i2 = (unsigned)__double_as_longlong(k2) & 0xFFFu;
        unsigned i3 = (unsigned)__double_as_longlong(k3) & 0xFFFu;
        float d0 = (float)k0, d1 = (float)k1, d2 = (float)k2, d3 = (float)k3;
        float w0 = __expf(-(d0 + 1e-8f) * 0.5f);
        float w1 = __expf(-(d1 + 1e-8f) * 0.5f);
        float w2 = __expf(-(d2 + 1e-8f) * 0.5f);
        float w3 = __expf(-(d3 + 1e-8f) * 0.5f);
        float inv = 1.0f / (w0 + w1 + w2 + w3 + 1e-8f);
        w0 *= inv; w1 *= inv; w2 *= inv; w3 *= inv;
        ushort2 g0 = *(const ushort2*)(xu + bbase + ((size_t)i0 << 7) + c);
        ushort2 g1 = *(const ushort2*)(xu + bbase + ((size_t)i1 << 7) + c);
        ushort2 g2 = *(const ushort2*)(xu + bbase + ((size_t)i2 << 7) + c);
        ushort2 g3 = *(const ushort2*)(xu + bbase + ((size_t)i3 << 7) + c);
        float ox = bb.x + w0 * __uint_as_float((unsigned)g0.x << 16)
                        + w1 * __uint_as_float((unsigned)g1.x << 16)
                        + w2 * __uint_as_float((unsigned)g2.x << 16)
                        + w3 * __uint_as_float((unsigned)g3.x << 16);
        float oy = bb.y + w0 * __uint_as_float((unsigned)g0.y << 16)
                        + w1 * __uint_as_float((unsigned)g1.y << 16)
                        + w2 * __uint_as_float((unsigned)g2.y << 16)
                        + w3 * __uint_as_float((unsigned)g3.y << 16);
        *(float2*)(out + (((size_t)(rowbase + k)) << 7) + c) = make_float2(ox, oy);
    }
}

extern "C" void kernel_launch(void* const* d_in, const int* in_sizes, int n_in,
                              void* d_out, int out_size, void* d_ws, size_t ws_size,
                              hipStream_t stream) {
    const float* x    = (const float*)d_in[0];  // [2,4096,128]
    const float* pos  = (const float*)d_in[1];  // [2,4096,3]
    const float* W    = (const float*)d_in[2];  // [128,128]
    const float* bias = (const float*)d_in[3];  // [128]
    float* out = (float*)d_out;                 // [2,4096,128] f32

    char* ws = (char*)d_ws;
    __hip_bfloat16* xWb = (__hip_bfloat16*)ws;                       // 2 MB
    float4* pos4 = (float4*)(ws + (size_t)NROWS * DIM * 2);          // 128 KB

    k1_prep_gemm<<<GEMM_BLOCKS + NROWS / 256, 256, 0, stream>>>(x, pos, W, pos4, xWb);
    topk_agg<<<NROWS / 4, 256, 0, stream>>>(pos4, xWb, bias, out);
}

// Round 8
// 88.036 us; speedup vs baseline: 1.1607x; 1.0085x over previous
//
#include <hip/hip_runtime.h>
#include <hip/hip_bf16.h>

#define NPTS 4096
#define NROWS 8192   // B*N
#define DIM 128
#define TILE 2048    // points per LDS tile (24 KB)
#define GEMM_BLOCKS 1024

typedef __attribute__((ext_vector_type(8))) short bf16x8;
typedef __attribute__((ext_vector_type(4))) float f32x4;

// ---------- K1: xW = x @ W via bf16 MFMA (R7-verified, self-contained W) ----------
__global__ __launch_bounds__(256) void xw_mfma(const float* __restrict__ x,
                                               const float* __restrict__ W,
                                               __hip_bfloat16* __restrict__ xWb) {
    int wave = threadIdx.x >> 6;
    int lane = threadIdx.x & 63;
    int tile = blockIdx.x * 4 + wave;          // 0..4095
    int m0 = (tile >> 3) << 4;
    int n0 = (tile & 7) << 4;
    int r = lane & 15;
    int kg = lane >> 4;                        // 0..3
    const float* xr = x + (size_t)(m0 + r) * DIM + kg * 8;
    const float* wc = W + (size_t)(kg * 8) * DIM + (n0 + r);
    f32x4 acc = {0.f, 0.f, 0.f, 0.f};
    union { __hip_bfloat16 h; short s; } u;
#pragma unroll
    for (int kb = 0; kb < 4; ++kb) {
        float4 a0 = *(const float4*)(xr + kb * 32);
        float4 a1 = *(const float4*)(xr + kb * 32 + 4);
        bf16x8 af, bf;
        u.h = __float2bfloat16(a0.x); af[0] = u.s;
        u.h = __float2bfloat16(a0.y); af[1] = u.s;
        u.h = __float2bfloat16(a0.z); af[2] = u.s;
        u.h = __float2bfloat16(a0.w); af[3] = u.s;
        u.h = __float2bfloat16(a1.x); af[4] = u.s;
        u.h = __float2bfloat16(a1.y); af[5] = u.s;
        u.h = __float2bfloat16(a1.z); af[6] = u.s;
        u.h = __float2bfloat16(a1.w); af[7] = u.s;
#pragma unroll
        for (int i = 0; i < 8; ++i) {
            u.h = __float2bfloat16(wc[(size_t)(kb * 32 + i) * DIM]);
            bf[i] = u.s;
        }
        acc = __builtin_amdgcn_mfma_f32_16x16x32_bf16(af, bf, acc, 0, 0, 0);
    }
    int col = n0 + r;
    int rbase = m0 + (kg << 2);
#pragma unroll
    for (int reg = 0; reg < 4; ++reg)
        xWb[(size_t)(rbase + reg) * DIM + col] = __float2bfloat16(acc[reg]);
}

// ---------- exact f64 packed key: key = f64(d2) with low 12 bits = j ----------
__device__ __forceinline__ double mkkey(float d2, int j) {
    return __longlong_as_double(__double_as_longlong((double)d2) |
                                (unsigned long long)(unsigned)j);
}

// sorted-ascending insert: 7 v_min/max_f64
__device__ __forceinline__ void kins(double& k0, double& k1, double& k2,
                                     double& k3, double s) {
    double c = fmax(k0, s); k0 = fmin(k0, s);
    double t = fmax(k1, c); k1 = fmin(k1, c); c = t;
    t = fmax(k2, c);        k2 = fmin(k2, c); c = t;
    k3 = fmin(k3, c);
}

// merge two sorted-asc 4-lists -> 4 smallest sorted: 12 v_min/max_f64
__device__ __forceinline__ void kmerge(double& a0, double& a1, double& a2,
                                       double& a3, double b0, double b1,
                                       double b2, double b3) {
    double m0 = fmin(a0, b3), m1 = fmin(a1, b2);
    double m2 = fmin(a2, b1), m3 = fmin(a3, b0);
    double t0 = fmin(m0, m2), t2 = fmax(m0, m2);
    double t1 = fmin(m1, m3), t3 = fmax(m1, m3);
    a0 = fmin(t0, t1); a1 = fmax(t0, t1);
    a2 = fmin(t2, t3); a3 = fmax(t2, t3);
}

// ---------- K2: LDS-staged topk. Block = 8 rows (2/wave), 2 tiles of 2048 pts.
// pos read from L2 ONCE PER BLOCK (5.6x less L2 traffic than per-wave streaming).
// LDS reads: stride-12B -> bank 3j%32, j vs j+32 same bank = 2-way (free, m136).
__global__ __launch_bounds__(256) void topk_agg(const float* __restrict__ pos,
                                                const __hip_bfloat16* __restrict__ xWb,
                                                const float* __restrict__ bias,
                                                float* __restrict__ out) {
    __shared__ float sp[TILE * 3];             // 24 KB
    int lane = threadIdx.x & 63;
    int wave = threadIdx.x >> 6;
    int rowbase = blockIdx.x * 8;              // 8 rows/block, never straddles batch
    int batch = rowbase >> 12;
    int ibase = rowbase & (NPTS - 1);
    const float* pb = pos + (size_t)batch * NPTS * 3;

    int r0 = ibase + wave * 2;
    float q0x = pb[3 * r0 + 0], q0y = pb[3 * r0 + 1], q0z = pb[3 * r0 + 2];
    float q1x = pb[3 * r0 + 3], q1y = pb[3 * r0 + 4], q1z = pb[3 * r0 + 5];

    const double INF = __builtin_inf();
    double a0 = INF, a1 = INF, a2 = INF, a3 = INF;   // row 2w keys
    double b0 = INF, b1 = INF, b2 = INF, b3 = INF;   // row 2w+1 keys

    for (int tile = 0; tile < 2; ++tile) {
        // cooperative global->LDS: 2048 pts = 1536 float4, 6 per thread
        const float4* src = (const float4*)(pb + (size_t)tile * TILE * 3);
        float4* dst = (float4*)sp;
#pragma unroll
        for (int i = 0; i < 6; ++i)
            dst[threadIdx.x * 6 + i] = src[threadIdx.x * 6 + i];
        __syncthreads();

        int jb = tile * TILE + lane;
#pragma unroll 4
        for (int it = 0; it < TILE / 64; ++it) {
            int jj = it * 64 + lane;
            float px = sp[3 * jj + 0];
            float py = sp[3 * jj + 1];
            float pz = sp[3 * jj + 2];
            int j = jb + it * 64;
            float dx = q0x - px, dy = q0y - py, dz = q0z - pz;
            float d2 = fmaf(dx, dx, fmaf(dy, dy, dz * dz));
            kins(a0, a1, a2, a3, mkkey(d2, j));
            dx = q1x - px; dy = q1y - py; dz = q1z - pz;
            d2 = fmaf(dx, dx, fmaf(dy, dy, dz * dz));
            kins(b0, b1, b2, b3, mkkey(d2, j));
        }
        __syncthreads();
    }

    // butterfly: 6 xor steps -> every lane holds final global top-4 per row
#pragma unroll
    for (int off = 1; off < 64; off <<= 1) {
        double p0 = __shfl_xor(a0, off), p1 = __shfl_xor(a1, off);
        double p2 = __shfl_xor(a2, off), p3 = __shfl_xor(a3, off);
        kmerge(a0, a1, a2, a3, p0, p1, p2, p3);
        p0 = __shfl_xor(b0, off); p1 = __shfl_xor(b1, off);
        p2 = __shfl_xor(b2, off); p3 = __shfl_xor(b3, off);
        kmerge(b0, b1, b2, b3, p0, p1, p2, p3);
    }

    // epilogue: wave writes its 2 rows; lane owns channels (2*lane, 2*lane+1)
    int c = lane << 1;
    float2 bb = *(const float2*)(bias + c);
    const unsigned short* xu = (const unsigned short*)xWb;
    size_t bbase = ((size_t)batch * NPTS) << 7;
#pragma unroll
    for (int k = 0; k < 2; ++k) {
        double k0 = k ? b0 : a0, k1 = k ? b1 : a1;
        double k2 = k ? b2 : a2, k3 = k ? b3 : a3;
        unsigned i0 = (unsigned)__double_as_longlong(k0) & 0xFFFu;
        unsigned i1 = (unsigned)__double_as_longlong(k1) & 0xFFFu;
        unsigned i2 = (unsigned)__double_as_longlong(k2) & 0xFFFu;
        unsigned i3 = (unsigned)__double_as_longlong(k3) & 0xFFFu;
        float d0 = (float)k0, d1 = (float)k1, d2 = (float)k2, d3 = (float)k3;
        float w0 = __expf(-(d0 + 1e-8f) * 0.5f);
        float w1 = __expf(-(d1 + 1e-8f) * 0.5f);
        float w2 = __expf(-(d2 + 1e-8f) * 0.5f);
        float w3 = __expf(-(d3 + 1e-8f) * 0.5f);
        float inv = 1.0f / (w0 + w1 + w2 + w3 + 1e-8f);
        w0 *= inv; w1 *= inv; w2 *= inv; w3 *= inv;
        ushort2 g0 = *(const ushort2*)(xu + bbase + ((size_t)i0 << 7) + c);
        ushort2 g1 = *(const ushort2*)(xu + bbase + ((size_t)i1 << 7) + c);
        ushort2 g2 = *(const ushort2*)(xu + bbase + ((size_t)i2 << 7) + c);
        ushort2 g3 = *(const ushort2*)(xu + bbase + ((size_t)i3 << 7) + c);
        float ox = bb.x + w0 * __uint_as_float((unsigned)g0.x << 16)
                        + w1 * __uint_as_float((unsigned)g1.x << 16)
                        + w2 * __uint_as_float((unsigned)g2.x << 16)
                        + w3 * __uint_as_float((unsigned)g3.x << 16);
        float oy = bb.y + w0 * __uint_as_float((unsigned)g0.y << 16)
                        + w1 * __uint_as_float((unsigned)g1.y << 16)
                        + w2 * __uint_as_float((unsigned)g2.y << 16)
                        + w3 * __uint_as_float((unsigned)g3.y << 16);
        *(float2*)(out + (((size_t)(rowbase + wave * 2 + k)) << 7) + c) =
            make_float2(ox, oy);
    }
}

extern "C" void kernel_launch(void* const* d_in, const int* in_sizes, int n_in,
                              void* d_out, int out_size, void* d_ws, size_t ws_size,
                              hipStream_t stream) {
    const float* x    = (const float*)d_in[0];  // [2,4096,128]
    const float* pos  = (const float*)d_in[1];  // [2,4096,3]
    const float* W    = (const float*)d_in[2];  // [128,128]
    const float* bias = (const float*)d_in[3];  // [128]
    float* out = (float*)d_out;                 // [2,4096,128] f32

    __hip_bfloat16* xWb = (__hip_bfloat16*)d_ws;   // 2 MB scratch

    xw_mfma<<<GEMM_BLOCKS, 256, 0, stream>>>(x, W, xWb);
    topk_agg<<<NROWS / 8, 256, 0, stream>>>(pos, xWb, bias, out);
}